// Round 8
// baseline (284.590 us; speedup 1.0000x reference)
//
#include <hip/hip_runtime.h>
#include <hip/hip_bf16.h>
#include <math.h>

#define B_  8
#define L_  4096
#define T_  128
#define DH  1024
#define DG  256
#define DP  256
#define BK  64
#define BK2 128        // big-K tile for the two large kernels
#define ZCH 8          // z split-K chunks

typedef short bf16x8 __attribute__((ext_vector_type(8)));
typedef float f32x4  __attribute__((ext_vector_type(4)));

#define AS1(p) ((const __attribute__((address_space(1))) void*)(p))
#define AS3(p) ((__attribute__((address_space(3))) void*)(p))

__device__ __forceinline__ unsigned short f2bf(float f) {
    unsigned u = __float_as_uint(f);
    unsigned r = (u + 0x7FFFu + ((u >> 16) & 1u)) >> 16;  // RNE
    return (unsigned short)r;
}
__device__ __forceinline__ int rot4(int d) {               // swizzle rotation, multiple of 4
    return (((d & 7) + ((d >> 3) & 7)) << 2) & 63;
}

// ---------------- Kernel W: Wct[d,g] = (1/16) * sum_p Wk[d,p] * Wq[g,p]   (bf16 out)
__global__ __launch_bounds__(256) void wct_kernel(const float* __restrict__ Wk,
                                                  const float* __restrict__ Wq,
                                                  unsigned short* __restrict__ Wct) {
    __shared__ __attribute__((aligned(16))) unsigned short As[128 * BK];
    __shared__ __attribute__((aligned(16))) unsigned short Bs[64 * BK];
    const int n0 = blockIdx.x * 64, m0 = blockIdx.y * 128;
    const int tid = threadIdx.x, wave = tid >> 6, lane = tid & 63;
    const int lm = lane & 15, quad = lane >> 4;
    const int wm = wave >> 1, wn = wave & 1;
    const int bc = (tid & 15) * 4, br = tid >> 4;
    f32x4 acc[4][2] = {};

    for (int k0 = 0; k0 < DP; k0 += BK) {
        #pragma unroll
        for (int s = 0; s < 8; ++s) {
            const int row = br + s * 16;
            const float4 v = *(const float4*)(Wk + (size_t)(m0 + row) * DP + k0 + bc);
            ushort4 p; p.x = f2bf(v.x); p.y = f2bf(v.y); p.z = f2bf(v.z); p.w = f2bf(v.w);
            *(ushort4*)(&As[row * BK + bc]) = p;
        }
        #pragma unroll
        for (int s = 0; s < 4; ++s) {
            const int row = br + s * 16;
            const float4 v = *(const float4*)(Wq + (size_t)(n0 + row) * DP + k0 + bc);
            ushort4 p; p.x = f2bf(v.x); p.y = f2bf(v.y); p.z = f2bf(v.z); p.w = f2bf(v.w);
            *(ushort4*)(&Bs[row * BK + bc]) = p;
        }
        __syncthreads();
        #pragma unroll
        for (int ks = 0; ks < 2; ++ks) {
            bf16x8 a[4], bf[2];
            #pragma unroll
            for (int i = 0; i < 4; ++i)
                a[i] = *(const bf16x8*)(&As[(wm * 64 + i * 16 + lm) * BK + ks * 32 + quad * 8]);
            #pragma unroll
            for (int j = 0; j < 2; ++j)
                bf[j] = *(const bf16x8*)(&Bs[(wn * 32 + j * 16 + lm) * BK + ks * 32 + quad * 8]);
            #pragma unroll
            for (int i = 0; i < 4; ++i)
                #pragma unroll
                for (int j = 0; j < 2; ++j)
                    acc[i][j] = __builtin_amdgcn_mfma_f32_16x16x32_bf16(a[i], bf[j], acc[i][j], 0, 0, 0);
        }
        __syncthreads();
    }
    unsigned short* Cb = Wct + (size_t)m0 * DG + n0;
    #pragma unroll
    for (int i = 0; i < 4; ++i)
        #pragma unroll
        for (int j = 0; j < 2; ++j)
            #pragma unroll
            for (int r = 0; r < 4; ++r)
                Cb[(size_t)(wm * 64 + i * 16 + quad * 4 + r) * DG + wn * 32 + j * 16 + lm] =
                    f2bf(acc[i][j][r] * 0.0625f);
}

// ---------------- Kernel Q: Qk[bt,d] = sum_g G[bt,g] * Wct[d,g]   (bf16 out)
__global__ __launch_bounds__(256) void qproj_kernel(const float* __restrict__ G,
                                                    const unsigned short* __restrict__ Wct,
                                                    unsigned short* __restrict__ Qk) {
    __shared__ __attribute__((aligned(16))) unsigned short As[128 * BK];
    __shared__ __attribute__((aligned(16))) unsigned short Bs[64 * BK];
    const int n0 = blockIdx.x * 64, m0 = blockIdx.y * 128;
    const int tid = threadIdx.x, wave = tid >> 6, lane = tid & 63;
    const int lm = lane & 15, quad = lane >> 4;
    const int wm = wave >> 1, wn = wave & 1;
    const int bc = (tid & 15) * 4, br = tid >> 4;
    const int ar = lane >> 3, akb = (lane & 7) * 8;
    f32x4 acc[4][2] = {};

    for (int k0 = 0; k0 < DG; k0 += BK) {
        #pragma unroll
        for (int s = 0; s < 8; ++s) {
            const int row = br + s * 16;
            const float4 v = *(const float4*)(G + (size_t)(m0 + row) * DG + k0 + bc);
            ushort4 p; p.x = f2bf(v.x); p.y = f2bf(v.y); p.z = f2bf(v.z); p.w = f2bf(v.w);
            *(ushort4*)(&As[row * BK + bc]) = p;
        }
        #pragma unroll
        for (int s = 0; s < 2; ++s) {
            const int rowb = s * 32 + wave * 8;
            const unsigned short* gp = Wct + (size_t)(n0 + rowb + ar) * DG + k0 + akb;
            __builtin_amdgcn_global_load_lds(AS1(gp), AS3(&Bs[rowb * BK]), 16, 0, 0);
        }
        __syncthreads();
        #pragma unroll
        for (int ks = 0; ks < 2; ++ks) {
            bf16x8 a[4], bf[2];
            #pragma unroll
            for (int i = 0; i < 4; ++i)
                a[i] = *(const bf16x8*)(&As[(wm * 64 + i * 16 + lm) * BK + ks * 32 + quad * 8]);
            #pragma unroll
            for (int j = 0; j < 2; ++j)
                bf[j] = *(const bf16x8*)(&Bs[(wn * 32 + j * 16 + lm) * BK + ks * 32 + quad * 8]);
            #pragma unroll
            for (int i = 0; i < 4; ++i)
                #pragma unroll
                for (int j = 0; j < 2; ++j)
                    acc[i][j] = __builtin_amdgcn_mfma_f32_16x16x32_bf16(a[i], bf[j], acc[i][j], 0, 0, 0);
        }
        __syncthreads();
    }
    unsigned short* Cb = Qk + (size_t)m0 * DH + n0;
    #pragma unroll
    for (int i = 0; i < 4; ++i)
        #pragma unroll
        for (int j = 0; j < 2; ++j)
            #pragma unroll
            for (int r = 0; r < 4; ++r)
                Cb[(size_t)(wm * 64 + i * 16 + quad * 4 + r) * DH + wn * 32 + j * 16 + lm] =
                    f2bf(acc[i][j][r]);
}

// ---------------- Kernel S: fused logits+exp, BK2=128 (8 k-iters, halved barriers)
// alpha_un[b,t,l] = mask? 0 : exp(Qk[b,t,:].H[b,l,:]); accumulates rowsum.
// 1D grid 512: b = id&7 (XCD-clustered => Qk L2-resident), l-tile = id>>3.
__global__ __launch_bounds__(256, 2) void fusedsm_kernel(const unsigned short* __restrict__ Qk,
                                                         const float* __restrict__ H,
                                                         const int* __restrict__ mask,
                                                         unsigned short* __restrict__ alpha,
                                                         float* __restrict__ rowsum) {
    __shared__ __attribute__((aligned(16))) unsigned short As[T_ * BK2];  // [t][k] 32 KB
    __shared__ __attribute__((aligned(16))) unsigned short Bs[64 * BK2];  // [l][k] 16 KB
    __shared__ float rs[T_];
    const int id = blockIdx.x;
    const int b = id & 7, l0 = (id >> 3) * 64;
    const int tid = threadIdx.x, wave = tid >> 6, lane = tid & 63;
    const unsigned short* Ab = Qk + (size_t)b * T_ * DH;
    const float*          Hb = H + ((size_t)b * L_ + l0) * DH;

    const int lm = lane & 15, quad = lane >> 4;
    const int wm = wave >> 1, wn = wave & 1;
    f32x4 acc[4][2] = {};
    const int ar = lane >> 4, akb = (lane & 15) * 8;   // A async: 4 rows x 256B per issue
    const int col2 = tid & 63, rowg = tid >> 6;        // B stage: ushort2 conflict-free map

    if (tid < T_) rs[tid] = 0.f;

    for (int k0 = 0; k0 < DH; k0 += BK2) {
        #pragma unroll
        for (int s = 0; s < 8; ++s) {   // A: Qk 128 t-rows x 128 k, async (8 x 1KB per wave)
            const int rowb = s * 16 + wave * 4;
            const unsigned short* gp = Ab + (size_t)(rowb + ar) * DH + k0 + akb;
            __builtin_amdgcn_global_load_lds(AS1(gp), AS3(&As[rowb * BK2]), 16, 0, 0);
        }
        #pragma unroll
        for (int s = 0; s < 16; ++s) {  // B: H 64 l-rows x 128 k fp32 -> bf16 (2-way stores, free)
            const int row = rowg * 16 + s;
            const float2 v = *(const float2*)(Hb + (size_t)row * DH + k0 + col2 * 2);
            ushort2 p; p.x = f2bf(v.x); p.y = f2bf(v.y);
            *(ushort2*)(&Bs[row * BK2 + col2 * 2]) = p;
        }
        __syncthreads();
        #pragma unroll
        for (int ks = 0; ks < 4; ++ks) {
            bf16x8 a[4], bf[2];
            #pragma unroll
            for (int i = 0; i < 4; ++i)
                a[i] = *(const bf16x8*)(&As[(wm * 64 + i * 16 + lm) * BK2 + ks * 32 + quad * 8]);
            #pragma unroll
            for (int j = 0; j < 2; ++j)
                bf[j] = *(const bf16x8*)(&Bs[(wn * 32 + j * 16 + lm) * BK2 + ks * 32 + quad * 8]);
            #pragma unroll
            for (int i = 0; i < 4; ++i)
                #pragma unroll
                for (int j = 0; j < 2; ++j)
                    acc[i][j] = __builtin_amdgcn_mfma_f32_16x16x32_bf16(a[i], bf[j], acc[i][j], 0, 0, 0);
        }
        __syncthreads();
    }

    // epilogue: mask, exp, store bf16 alpha, accumulate row sums
    const int c0 = l0 + wn * 32 + lm;
    const int mk0 = mask[(size_t)b * L_ + c0];
    const int mk1 = mask[(size_t)b * L_ + c0 + 16];
    unsigned short* Arow = alpha + (size_t)b * T_ * L_ + l0 + wn * 32 + lm;
    #pragma unroll
    for (int i = 0; i < 4; ++i) {
        #pragma unroll
        for (int r = 0; r < 4; ++r) {
            const int row = wm * 64 + i * 16 + quad * 4 + r;
            float e0 = mk0 ? 0.f : __expf(acc[i][0][r]);
            float e1 = mk1 ? 0.f : __expf(acc[i][1][r]);
            Arow[(size_t)row * L_]      = f2bf(e0);
            Arow[(size_t)row * L_ + 16] = f2bf(e1);
            float part = e0 + e1;
            part += __shfl_xor(part, 1, 64);
            part += __shfl_xor(part, 2, 64);
            part += __shfl_xor(part, 4, 64);
            part += __shfl_xor(part, 8, 64);
            if (lm == 0) atomicAdd(&rs[row], part);
        }
    }
    __syncthreads();
    if (tid < T_) atomicAdd(&rowsum[(size_t)b * T_ + tid], rs[tid]);
}

// ---------------- Kernel 4: z-partials = alpha_un(bf16) . H(fp32->bf16, swizzled LDS transpose)
// BK2=128 (4 k-iters). 1D grid 512: b = id&7 (XCD-clustered => alpha L2-resident),
// ch = (id>>3)&7, d-tile = id>>6. tile 128t x 128d.
__global__ __launch_bounds__(256, 2) void z_kernel(const unsigned short* __restrict__ alpha,
                                                   const float* __restrict__ H,
                                                   float* __restrict__ part) {
    __shared__ __attribute__((aligned(16))) unsigned short As[T_ * BK2];  // [t][l] 32 KB
    __shared__ __attribute__((aligned(16))) unsigned B32[128 * 64];       // [d][lp] swizzled, 32 KB
    const int id = blockIdx.x;
    const int b = id & 7, ch = (id >> 3) & 7, d0 = (id >> 6) * 128;
    const int tid = threadIdx.x, wave = tid >> 6, lane = tid & 63;
    const int Lc = L_ / ZCH;                       // 512
    const unsigned short* Ab = alpha + (size_t)b * T_ * L_ + ch * Lc;
    const float*          Hb = H + ((size_t)b * L_ + ch * Lc) * DH + d0;

    const int lm = lane & 15, quad = lane >> 4;
    const int wm = wave >> 1, wn = wave & 1;
    f32x4 acc[4][4] = {};
    const int ar = lane >> 4, akb = (lane & 15) * 8;
    const int dg = tid & 15, lph = tid >> 4;       // dg: d-octet, lph: 4-l-row group

    for (int k0 = 0; k0 < Lc; k0 += BK2) {
        #pragma unroll
        for (int s = 0; s < 8; ++s) {   // A: alpha 128 t-rows x 128 l, async
            const int rowb = s * 16 + wave * 4;
            const unsigned short* gp = Ab + (size_t)(rowb + ar) * L_ + k0 + akb;
            __builtin_amdgcn_global_load_lds(AS1(gp), AS3(&As[rowb * BK2]), 16, 0, 0);
        }
        // B: H 128 l-rows x 128 d fp32 -> transposed bf16, l-pairs in uint, rot swizzle
        #pragma unroll
        for (int h = 0; h < 2; ++h) {
            const float* r = Hb + (size_t)(k0 + h * 64 + 4 * lph) * DH + dg * 8;
            float v[4][8];
            #pragma unroll
            for (int rr = 0; rr < 4; ++rr) {
                const float4 a = *(const float4*)(r + (size_t)rr * DH);
                const float4 c = *(const float4*)(r + (size_t)rr * DH + 4);
                v[rr][0] = a.x; v[rr][1] = a.y; v[rr][2] = a.z; v[rr][3] = a.w;
                v[rr][4] = c.x; v[rr][5] = c.y; v[rr][6] = c.z; v[rr][7] = c.w;
            }
            const int lp0 = h * 32 + 2 * lph;
            #pragma unroll
            for (int i = 0; i < 8; ++i) {
                const int d   = dg * 8 + i;
                const int rot = rot4(d);
                B32[d * 64 + ((lp0 + rot) & 63)] =
                    (unsigned)f2bf(v[0][i]) | ((unsigned)f2bf(v[1][i]) << 16);
                B32[d * 64 + ((lp0 + 1 + rot) & 63)] =
                    (unsigned)f2bf(v[2][i]) | ((unsigned)f2bf(v[3][i]) << 16);
            }
        }
        __syncthreads();
        #pragma unroll
        for (int ks = 0; ks < 4; ++ks) {
            bf16x8 a[4], bf[4];
            #pragma unroll
            for (int i = 0; i < 4; ++i)
                a[i] = *(const bf16x8*)(&As[(wm * 64 + i * 16 + lm) * BK2 + ks * 32 + quad * 8]);
            #pragma unroll
            for (int j = 0; j < 4; ++j) {
                const int d = wn * 64 + j * 16 + lm;
                bf[j] = *(const bf16x8*)(&B32[d * 64 + ((ks * 16 + quad * 4 + rot4(d)) & 63)]);
            }
            #pragma unroll
            for (int i = 0; i < 4; ++i)
                #pragma unroll
                for (int j = 0; j < 4; ++j)
                    acc[i][j] = __builtin_amdgcn_mfma_f32_16x16x32_bf16(a[i], bf[j], acc[i][j], 0, 0, 0);
        }
        __syncthreads();
    }
    float* Cb = part + (((size_t)ch * B_ + b) * T_) * DH + d0;
    #pragma unroll
    for (int i = 0; i < 4; ++i)
        #pragma unroll
        for (int j = 0; j < 4; ++j)
            #pragma unroll
            for (int r = 0; r < 4; ++r)
                Cb[(size_t)(wm * 64 + i * 16 + quad * 4 + r) * DH + wn * 64 + j * 16 + lm] = acc[i][j][r];
}

// ---------------- Kernel 5: Z = (sum of ZCH partial chunks) / rowsum
__global__ __launch_bounds__(256) void zreduce_kernel(const float* __restrict__ p,
                                                      const float* __restrict__ rowsum,
                                                      float* __restrict__ Z) {
    const size_t n = (size_t)B_ * T_ * DH;
    const size_t i = ((size_t)blockIdx.x * 256 + threadIdx.x) * 4;
    const int row = (int)(i >> 10);                // i / DH
    const float inv = 1.0f / rowsum[row];
    float4 o = {0.f, 0.f, 0.f, 0.f};
    #pragma unroll
    for (int c = 0; c < ZCH; ++c) {
        const float4 a = *(const float4*)(p + (size_t)c * n + i);
        o.x += a.x; o.y += a.y; o.z += a.z; o.w += a.w;
    }
    o.x *= inv; o.y *= inv; o.z *= inv; o.w *= inv;
    *(float4*)(Z + i) = o;
}

extern "C" void kernel_launch(void* const* d_in, const int* in_sizes, int n_in,
                              void* d_out, int out_size, void* d_ws, size_t ws_size,
                              hipStream_t stream) {
    const float* H    = (const float*)d_in[0];
    const float* G    = (const float*)d_in[1];
    const int*   mask = (const int*)d_in[2];
    const float* Wk   = (const float*)d_in[3];
    const float* Wq   = (const float*)d_in[4];
    float* Z = (float*)d_out;

    char* ws = (char*)d_ws;
    unsigned short* Wct    = (unsigned short*)ws;                        // 512 KB
    unsigned short* Qk     = (unsigned short*)(ws + ((size_t)1 << 20));  //   2 MB
    unsigned short* alpha  = (unsigned short*)(ws + ((size_t)4 << 20));  // 8.4 MB
    float*          rowsum = (float*)(ws + ((size_t)13 << 20));          //   4 KB
    float*          zpart  = (float*)(ws + ((size_t)14 << 20));          // 33.6 MB

    hipMemsetAsync(rowsum, 0, (size_t)B_ * T_ * sizeof(float), stream);
    wct_kernel<<<dim3(DG / 64, DH / 128), 256, 0, stream>>>(Wk, Wq, Wct);
    qproj_kernel<<<dim3(DH / 64, (B_ * T_) / 128), 256, 0, stream>>>(G, Wct, Qk);
    fusedsm_kernel<<<512, 256, 0, stream>>>(Qk, H, mask, alpha, rowsum);
    z_kernel<<<512, 256, 0, stream>>>(alpha, H, zpart);
    zreduce_kernel<<<(B_ * T_ * DH / 4) / 256, 256, 0, stream>>>(zpart, rowsum, Z);
}